// Round 4
// baseline (934.863 us; speedup 1.0000x reference)
//
#include <hip/hip_runtime.h>

#define BATCH 512
#define TT 256
#define HH 256
#define HOR 22
#define ROWS 16

typedef __attribute__((ext_vector_type(8))) short short8x;   // 8 bf16 (4 VGPRs)
typedef __attribute__((ext_vector_type(4))) float f32x4;

__device__ __forceinline__ float rcp_(float x) { return __builtin_amdgcn_rcpf(x); }
__device__ __forceinline__ float sigmoidf_(float x) { return rcp_(1.0f + __expf(-x)); }
__device__ __forceinline__ float tanhf_(float x) {
    float e = __expf(-2.0f * fabsf(x));
    float t = (1.0f - e) * rcp_(1.0f + e);
    return copysignf(t, x);
}
__device__ __forceinline__ unsigned f2bf_rne(float f) {
    unsigned u = __float_as_uint(f);
    unsigned lsb = (u >> 16) & 1u;
    return (u + 0x7FFFu + lsb) >> 16;
}

// ---------------- prep: U matrices -> MFMA B-fragment layout ----------------
// B-frag for (gate, col-tile ct, K-tile kt): lane holds 8 bf16 of
// U[k][col] with col = ct*16 + (lane&15), k = kt*32 + (lane>>4)*8 + j.
__global__ __launch_bounds__(256) void prep_kernel(const float* __restrict__ Uz,
                                                   const float* __restrict__ Ur,
                                                   const float* __restrict__ Uh,
                                                   unsigned short* __restrict__ UB) {
    int tid = blockIdx.x * 256 + threadIdx.x;   // 0 .. 24575
    int gate = tid >> 13;                        // 3 gates x 8192
    int rem  = tid & 8191;
    int ct   = rem >> 9;                         // 0..15
    int kt   = (rem >> 6) & 7;                   // 0..7
    int lane = rem & 63;
    int col  = ct * 16 + (lane & 15);
    int kbase = kt * 32 + (lane >> 4) * 8;
    const float* src = (gate == 0) ? Uz : (gate == 1) ? Ur : Uh;
    unsigned v[4];
#pragma unroll
    for (int jp = 0; jp < 4; ++jp) {
        unsigned lo = f2bf_rne(src[(kbase + 2 * jp)     * HH + col]);
        unsigned hi = f2bf_rne(src[(kbase + 2 * jp + 1) * HH + col]);
        v[jp] = lo | (hi << 16);
    }
    ((uint4*)UB)[tid] = make_uint4(v[0], v[1], v[2], v[3]);
}

// ---------------- persistent GRU: 1 WG = 16 rows, 8 waves, 2 waves/SIMD ----------------
// Wave w owns output cols [32w, 32w+32) (col-tiles 2w, 2w+1) for all 3 gates:
// 48 B-frags = 192 regs -> AGPRs, read natively by MFMA (zero moves — the
// structural advantage over the round-1 dot2 version, where every AGPR use
// needed v_accvgpr_read).
// waves_per_eu(2,2): 2 waves/SIMD, 256-reg unified budget. Peak demand ~240:
//   192 weights + 16 (Cz+Ch, phase B) + 8 h_own + 4 xc + 4 sg + ~16 misc.
// Key trim vs round 2 (which spilled at this occupancy): Cz is computed in
// PHASE B (z not needed before the barrier; h-buffer still readable there),
// deleting the 8-reg zst carry and halving phase-A accumulators. Numerically
// bit-identical. 2 waves/SIMD hide the extra 8 h-fragment re-reads.
//
// A-fragment LDS map: element (row r, col c) at byte
//   (c>>5)*1024 + ((c>>3)&3)*256 + r*16 + (c&7)*2          (bijective, 8 KB)
// Reader lane l at kt reads byte kt*1024 + l*16 (+j*2) = same map with
// m=l&15, k=kt*32+(l>>4)*8+j — consistent with prep's B-slot convention.
//
// LDS map (bytes):
//   0     : hA buf0  (8 KB)   [epilogue: hsF 16x256 f32 spans both bufs]
//   8192  : hA buf1  (8 KB)
//   16384 : rhA      (8 KB)   [epilogue: hid 16x256 f32 spans rhA+params]
//   24576 : params   (8 KB)  8 x 256 f32
//   32768 : xs       (16 KB) 16 x 256 f32   [epilogue: sigL 16 f32]
__global__ __launch_bounds__(512) __attribute__((amdgpu_waves_per_eu(2, 2))) void gru_kernel(
    const float* __restrict__ x,
    const float* __restrict__ Wzw, const float* __restrict__ Wzb, const float* __restrict__ Uzb,
    const float* __restrict__ Wrw, const float* __restrict__ Wrb, const float* __restrict__ Urb,
    const float* __restrict__ Whw, const float* __restrict__ Whb, const float* __restrict__ Uhb,
    const float* __restrict__ Wgw, const float* __restrict__ Wgb,
    const float* __restrict__ om_raw, const float* __restrict__ al_raw,
    const float* __restrict__ be_raw, const float* __restrict__ gam,
    const float* __restrict__ fc1w, const float* __restrict__ fc1b,
    const float* __restrict__ fc2w, const float* __restrict__ fc2b,
    const unsigned short* __restrict__ UB,
    float* __restrict__ out) {

    __shared__ __align__(16) char lds[49152];

    const int t    = threadIdx.x;
    const int w    = t >> 6;        // wave 0..7
    const int lane = t & 63;
    const int n    = lane & 15;     // col within 16-col tile
    const int g    = lane >> 4;     // row group / k group
    const int b0   = blockIdx.x * ROWS;

    // ---- weights -> registers (overflow into AGPRs; MFMA reads them natively) ----
    short8x Wz[2][8], Wr[2][8], Wh[2][8];
    {
        const short8x* ub = (const short8x*)UB;
#pragma unroll
        for (int tile = 0; tile < 2; ++tile) {
            const int ct = 2 * w + tile;
#pragma unroll
            for (int kt = 0; kt < 8; ++kt) {
                Wz[tile][kt] = ub[((0 * 16 + ct) * 8 + kt) * 64 + lane];
                Wr[tile][kt] = ub[((1 * 16 + ct) * 8 + kt) * 64 + lane];
                Wh[tile][kt] = ub[((2 * 16 + ct) * 8 + kt) * 64 + lane];
            }
        }
    }

    // ---- stage x rows: xs[r][tp] ----
    {
        float* xsF = (float*)(lds + 32768);
#pragma unroll
        for (int it = 0; it < 8; ++it) {
            int i = t + it * 512;               // 0..4095
            xsF[i] = x[(b0 + (i >> 8)) * TT + (i & 255)];
        }
    }
    // ---- per-column param table ----
    {
        float* pF = (float*)(lds + 24576);
#pragma unroll
        for (int it = 0; it < 4; ++it) {
            int i = t + it * 512;               // 0..2047
            int p = i >> 8, c = i & 255;
            float v;
            switch (p) {
                case 0: v = Wzw[c]; break;
                case 1: v = Wzb[c] + Uzb[c]; break;
                case 2: v = Wrw[c]; break;
                case 3: v = Wrb[c] + Urb[c]; break;
                case 4: v = Whw[c]; break;
                case 5: v = Whb[c] + Uhb[c]; break;
                case 6: v = Wgw[c]; break;
                default: v = Wgb[c]; break;
            }
            pF[i] = v;
        }
    }
    // ---- zero h buffer 0 (full 8 KB) ----
    {
        unsigned* z0 = (unsigned*)lds;
#pragma unroll
        for (int it = 0; it < 4; ++it) z0[t + it * 512] = 0;
    }

    // scalar params (uniform -> SGPRs)
    const float omega = log1pf(__expf(om_raw[0])) + 1e-6f;
    const float aco   = sigmoidf_(al_raw[0]);
    const float bco   = sigmoidf_(be_raw[0]) * (1.0f - aco * 0.99f);
    const float gma   = gam[0];

    // address bases (imm-offset addressing)
    const int rdH    = lane * 16;                                         // + hbase + kt*1024
    const int rdR    = 16384 + lane * 16;                                 // + kt*1024
    const int wrBase = w * 1024 + (n >> 3) * 256 + g * 64 + (n & 7) * 2;  // + tile*512 + i*16
    const int pvOff  = 24576 + w * 128 + n * 4;                           // + p*1024 + tile*64
    const int xvOff  = 32768 + g * 4096;                                  // + i*1024 + tt*4

    f32x4 h_own[2];
    h_own[0] = (f32x4){0.f, 0.f, 0.f, 0.f};
    h_own[1] = (f32x4){0.f, 0.f, 0.f, 0.f};
    float sg[4] = {1e-6f, 1e-6f, 1e-6f, 1e-6f};

    __syncthreads();

    int hbase = 0;
    for (int tt = 0; tt < TT; ++tt) {
        float xc[4];
#pragma unroll
        for (int i = 0; i < 4; ++i)
            xc[i] = *(const float*)(lds + xvOff + i * 1024 + tt * 4);

        // ---- phase A: Cr = h @ Ur only (Cz deferred to phase B) ----
        f32x4 Cr[2];
        Cr[0] = (f32x4){0.f, 0.f, 0.f, 0.f};
        Cr[1] = (f32x4){0.f, 0.f, 0.f, 0.f};
#pragma unroll
        for (int kt = 0; kt < 8; ++kt) {
            short8x ah = *(const short8x*)(lds + hbase + rdH + kt * 1024);
            Cr[0] = __builtin_amdgcn_mfma_f32_16x16x32_bf16(ah, Wr[0][kt], Cr[0], 0, 0, 0);
            Cr[1] = __builtin_amdgcn_mfma_f32_16x16x32_bf16(ah, Wr[1][kt], Cr[1], 0, 0, 0);
        }
#pragma unroll
        for (int tile = 0; tile < 2; ++tile) {
            const float wrp = *(const float*)(lds + pvOff + 2 * 1024 + tile * 64);
            const float brp = *(const float*)(lds + pvOff + 3 * 1024 + tile * 64);
#pragma unroll
            for (int i = 0; i < 4; ++i) {
                float rv = sigmoidf_(Cr[tile][i] + xc[i] * wrp + brp);
                float rh = rv * h_own[tile][i];
                *(unsigned short*)(lds + 16384 + wrBase + tile * 512 + i * 16) =
                    (unsigned short)f2bf_rne(rh);
            }
        }
        __syncthreads();

        // ---- phase B: Cz = h @ Uz, Ch = (r*h) @ Uh ----
        f32x4 Cz[2], Ch[2];
        Cz[0] = (f32x4){0.f, 0.f, 0.f, 0.f};
        Cz[1] = (f32x4){0.f, 0.f, 0.f, 0.f};
        Ch[0] = (f32x4){0.f, 0.f, 0.f, 0.f};
        Ch[1] = (f32x4){0.f, 0.f, 0.f, 0.f};
#pragma unroll
        for (int kt = 0; kt < 8; ++kt) {
            short8x ah = *(const short8x*)(lds + hbase + rdH + kt * 1024);
            short8x ar = *(const short8x*)(lds + rdR + kt * 1024);
            Cz[0] = __builtin_amdgcn_mfma_f32_16x16x32_bf16(ah, Wz[0][kt], Cz[0], 0, 0, 0);
            Cz[1] = __builtin_amdgcn_mfma_f32_16x16x32_bf16(ah, Wz[1][kt], Cz[1], 0, 0, 0);
            Ch[0] = __builtin_amdgcn_mfma_f32_16x16x32_bf16(ar, Wh[0][kt], Ch[0], 0, 0, 0);
            Ch[1] = __builtin_amdgcn_mfma_f32_16x16x32_bf16(ar, Wh[1][kt], Ch[1], 0, 0, 0);
        }
        // garch recurrence per owned row (uses x[tt-1])
        float gv[4];
#pragma unroll
        for (int i = 0; i < 4; ++i) {
            float xp = *(const float*)(lds + xvOff + i * 1024 + tt * 4 - 4);
            float ep = (tt == 0) ? 1e-6f : xp * xp;
            gv[i] = omega + aco * ep + bco * sg[i];
            sg[i] = gv[i];
        }
        // elementwise z, h_new; write h (bf16, A-frag layout, other buffer)
#pragma unroll
        for (int tile = 0; tile < 2; ++tile) {
            const float wzp = *(const float*)(lds + pvOff + 0 * 1024 + tile * 64);
            const float bzp = *(const float*)(lds + pvOff + 1 * 1024 + tile * 64);
            const float whp = *(const float*)(lds + pvOff + 4 * 1024 + tile * 64);
            const float bhp = *(const float*)(lds + pvOff + 5 * 1024 + tile * 64);
            const float wgp = *(const float*)(lds + pvOff + 6 * 1024 + tile * 64);
            const float bgp = *(const float*)(lds + pvOff + 7 * 1024 + tile * 64);
#pragma unroll
            for (int i = 0; i < 4; ++i) {
                float zv   = sigmoidf_(Cz[tile][i] + xc[i] * wzp + bzp);
                float htld = tanhf_(Ch[tile][i] + xc[i] * whp + bhp);
                float hh   = (1.f - zv) * htld + zv * h_own[tile][i];
                float hn   = tanhf_(hh + gma * (gv[i] * wgp + bgp));
                h_own[tile][i] = hn;
                *(unsigned short*)(lds + (hbase ^ 8192) + wrBase + tile * 512 + i * 16) =
                    (unsigned short)f2bf_rne(hn);
            }
        }
        hbase ^= 8192;
        __syncthreads();
    }

    // ---- stash exact fp32 h (overlay hA bufs, 16 KB) + sigma_sq ----
    {
        float* hsF = (float*)lds;
#pragma unroll
        for (int tile = 0; tile < 2; ++tile)
#pragma unroll
            for (int i = 0; i < 4; ++i)
                hsF[(g * 4 + i) * 256 + (2 * w + tile) * 16 + n] = h_own[tile][i];
        if (w == 0 && n == 0) {
            float* sigL = (float*)(lds + 32768);
#pragma unroll
            for (int i = 0; i < 4; ++i) sigL[g * 4 + i] = sg[i];
        }
    }
    __syncthreads();

    // ---- head: hid = relu(h @ fc1 + b1) ----
    {
        const int j = t & 255, half = t >> 8;   // half: rows half*8 .. +7
        const float* hsF = (const float*)lds;
        float acc[8];
#pragma unroll
        for (int r = 0; r < 8; ++r) acc[r] = 0.f;
#pragma unroll 4
        for (int k = 0; k < HH; ++k) {
            float wv = fc1w[k * HH + j];
#pragma unroll
            for (int r = 0; r < 8; ++r) acc[r] += hsF[(half * 8 + r) * 256 + k] * wv;
        }
        float* hid = (float*)(lds + 16384);
        const float b1 = fc1b[j];
#pragma unroll
        for (int r = 0; r < 8; ++r) hid[(half * 8 + r) * 256 + j] = fmaxf(acc[r] + b1, 0.f);
    }
    __syncthreads();

    // ---- head: nn_scale / vol ----
    if (t < ROWS * HOR) {
        const int b = t / HOR, c = t % HOR;
        const float* hid = (const float*)(lds + 16384);
        float acc = fc2b[c];
        for (int k = 0; k < HH; ++k) acc += hid[b * 256 + k] * fc2w[k * HOR + c];
        const float sp = log1pf(__expf(acc));
        const float sgv = ((const float*)(lds + 32768))[b];
        const float vb = sqrtf(sgv + 1e-8f);
        float vol = vb * (1.0f + sp);
        vol = fminf(fmaxf(vol, 0.01f), 10.0f);
        out[(b0 + b) * HOR + c] = vol;
    }
    if (t < ROWS) out[BATCH * HOR + b0 + t] = ((const float*)(lds + 32768))[t];
}

extern "C" void kernel_launch(void* const* d_in, const int* in_sizes, int n_in,
                              void* d_out, int out_size, void* d_ws, size_t ws_size,
                              hipStream_t stream) {
    const float* x    = (const float*)d_in[0];
    const float* Wzw  = (const float*)d_in[1];
    const float* Wzb  = (const float*)d_in[2];
    const float* Uzw  = (const float*)d_in[3];
    const float* Uzb  = (const float*)d_in[4];
    const float* Wrw  = (const float*)d_in[5];
    const float* Wrb  = (const float*)d_in[6];
    const float* Urw  = (const float*)d_in[7];
    const float* Urb  = (const float*)d_in[8];
    const float* Whw  = (const float*)d_in[9];
    const float* Whb  = (const float*)d_in[10];
    const float* Uhw  = (const float*)d_in[11];
    const float* Uhb  = (const float*)d_in[12];
    const float* Wgw  = (const float*)d_in[13];
    const float* Wgb  = (const float*)d_in[14];
    const float* om   = (const float*)d_in[15];
    const float* al   = (const float*)d_in[16];
    const float* be   = (const float*)d_in[17];
    const float* ga   = (const float*)d_in[18];
    const float* fc1w = (const float*)d_in[19];
    const float* fc1b = (const float*)d_in[20];
    const float* fc2w = (const float*)d_in[21];
    const float* fc2b = (const float*)d_in[22];

    unsigned short* UB = (unsigned short*)d_ws;   // 24576 x 16B fragments = 384 KB

    prep_kernel<<<96, 256, 0, stream>>>(Uzw, Urw, Uhw, UB);
    gru_kernel<<<32, 512, 0, stream>>>(x, Wzw, Wzb, Uzb, Wrw, Wrb, Urb, Whw, Whb, Uhb,
                                       Wgw, Wgb, om, al, be, ga, fc1w, fc1b, fc2w, fc2b,
                                       UB, (float*)d_out);
}

// Round 5
// 613.963 us; speedup vs baseline: 1.5227x; 1.5227x over previous
//
#include <hip/hip_runtime.h>

#define BATCH 512
#define TT 256
#define HH 256
#define HOR 22
#define ROWS 16

typedef __attribute__((ext_vector_type(4))) float f32x4;

__device__ __forceinline__ float rcp_(float x) { return __builtin_amdgcn_rcpf(x); }
__device__ __forceinline__ float sigmoidf_(float x) { return rcp_(1.0f + __expf(-x)); }
__device__ __forceinline__ float tanhf_(float x) {
    float e = __expf(-2.0f * fabsf(x));
    float t = (1.0f - e) * rcp_(1.0f + e);
    return copysignf(t, x);
}
// pack 4 floats -> 4 fp8 e4m3 bytes (little-endian order v0..v3)
__device__ __forceinline__ unsigned pk4_fp8(float v0, float v1, float v2, float v3) {
    int w = 0;
    w = __builtin_amdgcn_cvt_pk_fp8_f32(v0, v1, w, false);
    w = __builtin_amdgcn_cvt_pk_fp8_f32(v2, v3, w, true);
    return (unsigned)w;
}
#define PIN64(v) asm volatile("" : "+v"(v))

// ---------------- prep: U matrices -> fp8 MFMA A-fragment layout ----------------
// A-frag for (gate, col-tile ct, kt): lane holds 8 fp8 of A[m][k] = U[k][col],
// col = ct*16 + (lane&15), k = kt*32 + (lane>>4)*8 + j (j = byte 0..7).
// Consistent-permutation: B side (h) uses the SAME (lanegroup, byte)->k map, so
// any internal k-wiring cancels in the contraction.
__global__ __launch_bounds__(256) void prep_kernel(const float* __restrict__ Uz,
                                                   const float* __restrict__ Ur,
                                                   const float* __restrict__ Uh,
                                                   uint2* __restrict__ UB) {
    int tid  = blockIdx.x * 256 + threadIdx.x;   // 0 .. 24575
    int gate = tid >> 13;                         // 3 gates x 8192
    int rem  = tid & 8191;
    int ct   = rem >> 9;                          // 0..15
    int kt   = (rem >> 6) & 7;                    // 0..7
    int lane = rem & 63;
    int col  = ct * 16 + (lane & 15);
    int kb   = kt * 32 + (lane >> 4) * 8;
    const float* src = (gate == 0) ? Uz : (gate == 1) ? Ur : Uh;
    float f[8];
#pragma unroll
    for (int j = 0; j < 8; ++j) f[j] = src[(kb + j) * HH + col];
    uint2 v;
    v.x = pk4_fp8(f[0], f[1], f[2], f[3]);
    v.y = pk4_fp8(f[4], f[5], f[6], f[7]);
    UB[tid] = v;
}

// ---------------- persistent GRU: 1 WG = 16 rows, 8 waves, fp8 MFMA ----------------
// Operand-swapped: mfma(A=U-cols, B=h-rows) -> D[m=U-col][n=batch].
// Wave w owns U-cols [32w,32w+32) (2 m-tiles) for all 3 gates:
//   48 fragments x 2 regs = 96 weight regs (vs 192 at bf16 — the R2/R4 spill
//   cliff). Demand ~155 << 256 budget at waves_per_eu(2,2): real slack at 2
//   waves/SIMD, which R3 showed is mandatory for latency hiding.
// Thread owns batch row n = lane&15 and cols 32w + mt*16 + (lane>>4)*4 + i.
// h/rh stored fp8 in B-frag layout; element (k=col, n) at byte
//   kt*512 + (n + 16*((k>>3)&3))*8 + (k&7),  kt = k>>5 == w  (each wave writes
//   only its own kt slice; the thread's 4 i-values are CONTIGUOUS bytes -> one
//   ds_write_b32 per m-tile).
//
// LDS map (bytes):
//   0     : hB buf0  (4 KB)
//   4096  : hB buf1  (4 KB)
//   8192  : rhB      (4 KB)
//   12288 : params   (8 KB)  8 planes x 256 f32
//   20480 : xs       (16.07 KB) 16 rows x 1028 B (pad: kills 16-way bank conflict)
//   36928 : sigL     (64 B)
//   epilogue overlays: hsF f32[16][256] at 0, hid f32[16][256] at 16384
__global__ __launch_bounds__(512) __attribute__((amdgpu_waves_per_eu(2, 2))) void gru_kernel(
    const float* __restrict__ x,
    const float* __restrict__ Wzw, const float* __restrict__ Wzb, const float* __restrict__ Uzb,
    const float* __restrict__ Wrw, const float* __restrict__ Wrb, const float* __restrict__ Urb,
    const float* __restrict__ Whw, const float* __restrict__ Whb, const float* __restrict__ Uhb,
    const float* __restrict__ Wgw, const float* __restrict__ Wgb,
    const float* __restrict__ om_raw, const float* __restrict__ al_raw,
    const float* __restrict__ be_raw, const float* __restrict__ gam,
    const float* __restrict__ fc1w, const float* __restrict__ fc1b,
    const float* __restrict__ fc2w, const float* __restrict__ fc2b,
    const long* __restrict__ UBL,
    float* __restrict__ out) {

    __shared__ __align__(16) char lds[36992];

    const int t    = threadIdx.x;
    const int w    = t >> 6;        // wave 0..7
    const int lane = t & 63;
    const int n    = lane & 15;     // owned batch row
    const int lg   = lane >> 4;     // lane group 0..3
    const int b0   = blockIdx.x * ROWS;

    // ---- weights: 96 VGPRs of fp8 fragments ----
    long Wz[2][8], Wr[2][8], Wh[2][8];
#pragma unroll
    for (int mt = 0; mt < 2; ++mt) {
        const int ct = 2 * w + mt;
#pragma unroll
        for (int kt = 0; kt < 8; ++kt) {
            Wz[mt][kt] = UBL[((0 * 16 + ct) * 8 + kt) * 64 + lane];
            Wr[mt][kt] = UBL[((1 * 16 + ct) * 8 + kt) * 64 + lane];
            Wh[mt][kt] = UBL[((2 * 16 + ct) * 8 + kt) * 64 + lane];
        }
    }
#pragma unroll
    for (int mt = 0; mt < 2; ++mt)
#pragma unroll
        for (int kt = 0; kt < 8; ++kt) { PIN64(Wz[mt][kt]); PIN64(Wr[mt][kt]); PIN64(Wh[mt][kt]); }

    // ---- stage x rows (padded 1028B stride) ----
#pragma unroll
    for (int it = 0; it < 8; ++it) {
        int i = t + it * 512;                   // 0..4095
        int r = i >> 8, tp = i & 255;
        *(float*)(lds + 20480 + r * 1028 + tp * 4) = x[(b0 + r) * TT + tp];
    }
    // ---- per-column param table ----
#pragma unroll
    for (int it = 0; it < 4; ++it) {
        int i = t + it * 512;                   // 0..2047
        int p = i >> 8, c = i & 255;
        float v;
        switch (p) {
            case 0: v = Wzw[c]; break;
            case 1: v = Wzb[c] + Uzb[c]; break;
            case 2: v = Wrw[c]; break;
            case 3: v = Wrb[c] + Urb[c]; break;
            case 4: v = Whw[c]; break;
            case 5: v = Whb[c] + Uhb[c]; break;
            case 6: v = Wgw[c]; break;
            default: v = Wgb[c]; break;
        }
        *(float*)(lds + 12288 + p * 1024 + c * 4) = v;
    }
    // ---- zero h buffer 0 ----
    ((unsigned*)lds)[t] = 0;
    ((unsigned*)lds)[t + 512] = 0;

    // scalar params (uniform -> SGPRs)
    const float omega = log1pf(__expf(om_raw[0])) + 1e-6f;
    const float aco   = sigmoidf_(al_raw[0]);
    const float bco   = sigmoidf_(be_raw[0]) * (1.0f - aco * 0.99f);
    const float gma   = gam[0];

    // address bases
    const int rdF = lane * 8;                                          // + buf + kt*512
    const int wrB = w * 512 + n * 8 + (lg >> 1) * 128 + (lg & 1) * 4;  // + mt*256
    const int pvB = 12288 + w * 128 + lg * 16;                         // + p*1024 + mt*64
    const int xvB = 20480 + n * 1028;                                  // + tt*4

    f32x4 h_own[2], zst[2];
    h_own[0] = (f32x4){0.f, 0.f, 0.f, 0.f};
    h_own[1] = (f32x4){0.f, 0.f, 0.f, 0.f};
    float sg = 1e-6f, xp = 0.f;

    __syncthreads();

    int hb = 0;
    for (int tt = 0; tt < TT; ++tt) {
        const float xc = *(const float*)(lds + xvB + tt * 4);

        // ---- phase A: Cz = h@Uz, Cr = h@Ur ----
        f32x4 Cz[2], Cr[2];
        Cz[0] = (f32x4){0.f, 0.f, 0.f, 0.f};
        Cz[1] = (f32x4){0.f, 0.f, 0.f, 0.f};
        Cr[0] = (f32x4){0.f, 0.f, 0.f, 0.f};
        Cr[1] = (f32x4){0.f, 0.f, 0.f, 0.f};
#pragma unroll
        for (int kt = 0; kt < 8; ++kt) {
            long hv = *(const long*)(lds + hb + rdF + kt * 512);
            Cz[0] = __builtin_amdgcn_mfma_f32_16x16x32_fp8_fp8(Wz[0][kt], hv, Cz[0], 0, 0, 0);
            Cz[1] = __builtin_amdgcn_mfma_f32_16x16x32_fp8_fp8(Wz[1][kt], hv, Cz[1], 0, 0, 0);
            Cr[0] = __builtin_amdgcn_mfma_f32_16x16x32_fp8_fp8(Wr[0][kt], hv, Cr[0], 0, 0, 0);
            Cr[1] = __builtin_amdgcn_mfma_f32_16x16x32_fp8_fp8(Wr[1][kt], hv, Cr[1], 0, 0, 0);
        }
        // elementwise z, r; write r*h (fp8, one b32 per m-tile)
#pragma unroll
        for (int mt = 0; mt < 2; ++mt) {
            f32x4 wzv = *(const f32x4*)(lds + pvB + 0 * 1024 + mt * 64);
            f32x4 bzv = *(const f32x4*)(lds + pvB + 1 * 1024 + mt * 64);
            f32x4 wrv = *(const f32x4*)(lds + pvB + 2 * 1024 + mt * 64);
            f32x4 brv = *(const f32x4*)(lds + pvB + 3 * 1024 + mt * 64);
            float rh[4];
#pragma unroll
            for (int i = 0; i < 4; ++i) {
                zst[mt][i] = sigmoidf_(Cz[mt][i] + xc * wzv[i] + bzv[i]);
                float rv   = sigmoidf_(Cr[mt][i] + xc * wrv[i] + brv[i]);
                rh[i]      = rv * h_own[mt][i];
            }
            *(unsigned*)(lds + 8192 + wrB + mt * 256) = pk4_fp8(rh[0], rh[1], rh[2], rh[3]);
        }
        __syncthreads();

        // ---- phase B: Ch = (r*h)@Uh ----
        f32x4 Ch[2];
        Ch[0] = (f32x4){0.f, 0.f, 0.f, 0.f};
        Ch[1] = (f32x4){0.f, 0.f, 0.f, 0.f};
#pragma unroll
        for (int kt = 0; kt < 8; ++kt) {
            long rv8 = *(const long*)(lds + 8192 + rdF + kt * 512);
            Ch[0] = __builtin_amdgcn_mfma_f32_16x16x32_fp8_fp8(Wh[0][kt], rv8, Ch[0], 0, 0, 0);
            Ch[1] = __builtin_amdgcn_mfma_f32_16x16x32_fp8_fp8(Wh[1][kt], rv8, Ch[1], 0, 0, 0);
        }
        // garch recurrence (row-n scalar; uses x[tt-1])
        float ep = (tt == 0) ? 1e-6f : xp * xp;
        float gv = omega + aco * ep + bco * sg;
        sg = gv;
        // elementwise h_new; write h (fp8, other buffer)
#pragma unroll
        for (int mt = 0; mt < 2; ++mt) {
            f32x4 whv = *(const f32x4*)(lds + pvB + 4 * 1024 + mt * 64);
            f32x4 bhv = *(const f32x4*)(lds + pvB + 5 * 1024 + mt * 64);
            f32x4 wgv = *(const f32x4*)(lds + pvB + 6 * 1024 + mt * 64);
            f32x4 bgv = *(const f32x4*)(lds + pvB + 7 * 1024 + mt * 64);
            float hn[4];
#pragma unroll
            for (int i = 0; i < 4; ++i) {
                float htld = tanhf_(Ch[mt][i] + xc * whv[i] + bhv[i]);
                float zv   = zst[mt][i];
                float hh   = (1.f - zv) * htld + zv * h_own[mt][i];
                hn[i]      = tanhf_(hh + gma * (gv * wgv[i] + bgv[i]));
                h_own[mt][i] = hn[i];
            }
            *(unsigned*)(lds + (hb ^ 4096) + wrB + mt * 256) = pk4_fp8(hn[0], hn[1], hn[2], hn[3]);
        }
        xp = xc;
        hb ^= 4096;
        __syncthreads();
    }

    // ---- stash exact fp32 h (overlay, 16 KB at 0) + sigma_sq ----
    {
        float* hsF = (float*)lds;
#pragma unroll
        for (int mt = 0; mt < 2; ++mt)
#pragma unroll
            for (int i = 0; i < 4; ++i)
                hsF[n * 256 + 32 * w + mt * 16 + lg * 4 + i] = h_own[mt][i];
        if (w == 0 && lg == 0) ((float*)(lds + 36928))[n] = sg;
    }
    __syncthreads();

    // ---- head: hid = relu(h @ fc1 + b1) ----
    {
        const int j = t & 255, half = t >> 8;   // rows half*8 .. +7
        const float* hsF = (const float*)lds;
        float acc[8];
#pragma unroll
        for (int r = 0; r < 8; ++r) acc[r] = 0.f;
#pragma unroll 4
        for (int k = 0; k < HH; ++k) {
            float wv = fc1w[k * HH + j];
#pragma unroll
            for (int r = 0; r < 8; ++r) acc[r] += hsF[(half * 8 + r) * 256 + k] * wv;
        }
        float* hid = (float*)(lds + 16384);
        const float b1 = fc1b[j];
#pragma unroll
        for (int r = 0; r < 8; ++r) hid[(half * 8 + r) * 256 + j] = fmaxf(acc[r] + b1, 0.f);
    }
    __syncthreads();

    // ---- head: nn_scale / vol ----
    if (t < ROWS * HOR) {
        const int b = t / HOR, c = t % HOR;
        const float* hid = (const float*)(lds + 16384);
        float acc = fc2b[c];
        for (int k = 0; k < HH; ++k) acc += hid[b * 256 + k] * fc2w[k * HOR + c];
        const float sp  = log1pf(__expf(acc));
        const float sgv = ((const float*)(lds + 36928))[b];
        const float vb  = sqrtf(sgv + 1e-8f);
        float vol = vb * (1.0f + sp);
        vol = fminf(fmaxf(vol, 0.01f), 10.0f);
        out[(b0 + b) * HOR + c] = vol;
    }
    if (t < ROWS) out[BATCH * HOR + b0 + t] = ((const float*)(lds + 36928))[t];
}

extern "C" void kernel_launch(void* const* d_in, const int* in_sizes, int n_in,
                              void* d_out, int out_size, void* d_ws, size_t ws_size,
                              hipStream_t stream) {
    const float* x    = (const float*)d_in[0];
    const float* Wzw  = (const float*)d_in[1];
    const float* Wzb  = (const float*)d_in[2];
    const float* Uzw  = (const float*)d_in[3];
    const float* Uzb  = (const float*)d_in[4];
    const float* Wrw  = (const float*)d_in[5];
    const float* Wrb  = (const float*)d_in[6];
    const float* Urw  = (const float*)d_in[7];
    const float* Urb  = (const float*)d_in[8];
    const float* Whw  = (const float*)d_in[9];
    const float* Whb  = (const float*)d_in[10];
    const float* Uhw  = (const float*)d_in[11];
    const float* Uhb  = (const float*)d_in[12];
    const float* Wgw  = (const float*)d_in[13];
    const float* Wgb  = (const float*)d_in[14];
    const float* om   = (const float*)d_in[15];
    const float* al   = (const float*)d_in[16];
    const float* be   = (const float*)d_in[17];
    const float* ga   = (const float*)d_in[18];
    const float* fc1w = (const float*)d_in[19];
    const float* fc1b = (const float*)d_in[20];
    const float* fc2w = (const float*)d_in[21];
    const float* fc2b = (const float*)d_in[22];

    uint2* UB = (uint2*)d_ws;   // 24576 x 8B fp8 fragments = 192 KB

    prep_kernel<<<96, 256, 0, stream>>>(Uzw, Urw, Uhw, UB);
    gru_kernel<<<32, 512, 0, stream>>>(x, Wzw, Wzb, Uzb, Wrw, Wrb, Urb, Whw, Whb, Uhb,
                                       Wgw, Wgb, om, al, be, ga, fc1w, fc1b, fc2w, fc2b,
                                       (const long*)UB, (float*)d_out);
}

// Round 6
// 574.600 us; speedup vs baseline: 1.6270x; 1.0685x over previous
//
#include <hip/hip_runtime.h>

#define BATCH 512
#define TT 256
#define HH 256
#define HOR 22
#define ROWS 16

typedef __attribute__((ext_vector_type(4))) float f32x4;

__device__ __forceinline__ float rcp_(float x) { return __builtin_amdgcn_rcpf(x); }
__device__ __forceinline__ float sigmoidf_(float x) { return rcp_(1.0f + __expf(-x)); }
__device__ __forceinline__ float tanhf_(float x) {
    float e = __expf(-2.0f * fabsf(x));
    float t = (1.0f - e) * rcp_(1.0f + e);
    return copysignf(t, x);
}
// pack 4 floats -> 4 fp8 e4m3 bytes (little-endian order v0..v3)
__device__ __forceinline__ unsigned pk4_fp8(float v0, float v1, float v2, float v3) {
    int w = 0;
    w = __builtin_amdgcn_cvt_pk_fp8_f32(v0, v1, w, false);
    w = __builtin_amdgcn_cvt_pk_fp8_f32(v2, v3, w, true);
    return (unsigned)w;
}
#define PIN64(v) asm volatile("" : "+v"(v))

// ---------------- prep: U matrices -> fp8 MFMA A-fragment layout ----------------
// A-frag for (gate, col-tile ct, kt): lane holds 8 fp8 of A[m][k] = U[k][col],
// col = ct*16 + (lane&15), k = kt*32 + (lane>>4)*8 + j (j = byte 0..7).
__global__ __launch_bounds__(256) void prep_kernel(const float* __restrict__ Uz,
                                                   const float* __restrict__ Ur,
                                                   const float* __restrict__ Uh,
                                                   uint2* __restrict__ UB) {
    int tid  = blockIdx.x * 256 + threadIdx.x;   // 0 .. 24575
    int gate = tid >> 13;                         // 3 gates x 8192
    int rem  = tid & 8191;
    int ct   = rem >> 9;                          // 0..15
    int kt   = (rem >> 6) & 7;                    // 0..7
    int lane = rem & 63;
    int col  = ct * 16 + (lane & 15);
    int kb   = kt * 32 + (lane >> 4) * 8;
    const float* src = (gate == 0) ? Uz : (gate == 1) ? Ur : Uh;
    float f[8];
#pragma unroll
    for (int j = 0; j < 8; ++j) f[j] = src[(kb + j) * HH + col];
    uint2 v;
    v.x = pk4_fp8(f[0], f[1], f[2], f[3]);
    v.y = pk4_fp8(f[4], f[5], f[6], f[7]);
    UB[tid] = v;
}

// ---------------- persistent GRU: 1 WG = 16 rows, 16 waves, 4 waves/SIMD ----------------
// R5 (8 waves, 2/SIMD) measured 65% VALUBusy + 35% stall per active CU; the
// occupancy lever (R3->R5: 1->2 waves = 1.6x) is extended to 4 waves/SIMD.
// Wave w owns ONE m-tile (U-cols [16w,16w+16)) for all 3 gates:
//   24 fragments x 2 regs = 48 weight regs; working set ~50 -> ~100 <= 128-reg
//   budget at waves_per_eu(4,4). Math bit-identical to R5 (same acc chains,
//   same elementwise); only ownership reorganized.
// Thread owns batch row n = lane&15, cols 16w + lg*4 + i (lg = lane>>4).
// h/rh stored fp8 in B-frag layout: element (k,n) at byte
//   (k>>5)*512 + (n + 16*((k>>3)&3))*8 + (k&7)
// Writer thread (w,lg,n): 4 contiguous bytes at
//   (w>>1)*512 + (n + 16*((2w + (lg>>1))&3))*8 + (lg&1)*4   (one ds_write_b32)
// Reader lane l, kt: byte kt*512 + l*8 (+j) — same map, verified bijective.
//
// LDS map (bytes):
//   0     : hB buf0  (4 KB)
//   4096  : hB buf1  (4 KB)
//   8192  : rhB      (4 KB)
//   12288 : params   (8 KB)  8 planes x 256 f32
//   20480 : xs       (16.07 KB) 16 rows x 1028 B (pad kills bank conflicts)
//   36928 : sigL     (64 B)
//   epilogue overlays: hsF f32[16][256] at 0, hid f32[16][256] at 16384
__global__ __launch_bounds__(1024) __attribute__((amdgpu_waves_per_eu(4, 4))) void gru_kernel(
    const float* __restrict__ x,
    const float* __restrict__ Wzw, const float* __restrict__ Wzb, const float* __restrict__ Uzb,
    const float* __restrict__ Wrw, const float* __restrict__ Wrb, const float* __restrict__ Urb,
    const float* __restrict__ Whw, const float* __restrict__ Whb, const float* __restrict__ Uhb,
    const float* __restrict__ Wgw, const float* __restrict__ Wgb,
    const float* __restrict__ om_raw, const float* __restrict__ al_raw,
    const float* __restrict__ be_raw, const float* __restrict__ gam,
    const float* __restrict__ fc1w, const float* __restrict__ fc1b,
    const float* __restrict__ fc2w, const float* __restrict__ fc2b,
    const long* __restrict__ UBL,
    float* __restrict__ out) {

    __shared__ __align__(16) char lds[36992];

    const int t    = threadIdx.x;
    const int w    = t >> 6;        // wave 0..15, owns m-tile w
    const int lane = t & 63;
    const int n    = lane & 15;     // owned batch row
    const int lg   = lane >> 4;     // lane group 0..3
    const int b0   = blockIdx.x * ROWS;

    // ---- weights: 48 VGPRs of fp8 fragments ----
    long Wz[8], Wr[8], Wh[8];
#pragma unroll
    for (int kt = 0; kt < 8; ++kt) {
        Wz[kt] = UBL[((0 * 16 + w) * 8 + kt) * 64 + lane];
        Wr[kt] = UBL[((1 * 16 + w) * 8 + kt) * 64 + lane];
        Wh[kt] = UBL[((2 * 16 + w) * 8 + kt) * 64 + lane];
    }
#pragma unroll
    for (int kt = 0; kt < 8; ++kt) { PIN64(Wz[kt]); PIN64(Wr[kt]); PIN64(Wh[kt]); }

    // ---- stage x rows (padded 1028B stride) ----
#pragma unroll
    for (int it = 0; it < 4; ++it) {
        int i = t + it * 1024;                  // 0..4095
        int r = i >> 8, tp = i & 255;
        *(float*)(lds + 20480 + r * 1028 + tp * 4) = x[(b0 + r) * TT + tp];
    }
    // ---- per-column param table ----
#pragma unroll
    for (int it = 0; it < 2; ++it) {
        int i = t + it * 1024;                  // 0..2047
        int p = i >> 8, c = i & 255;
        float v;
        switch (p) {
            case 0: v = Wzw[c]; break;
            case 1: v = Wzb[c] + Uzb[c]; break;
            case 2: v = Wrw[c]; break;
            case 3: v = Wrb[c] + Urb[c]; break;
            case 4: v = Whw[c]; break;
            case 5: v = Whb[c] + Uhb[c]; break;
            case 6: v = Wgw[c]; break;
            default: v = Wgb[c]; break;
        }
        *(float*)(lds + 12288 + p * 1024 + c * 4) = v;
    }
    // ---- zero h buffer 0 ----
    ((unsigned*)lds)[t] = 0;

    // scalar params (uniform -> SGPRs)
    const float omega = log1pf(__expf(om_raw[0])) + 1e-6f;
    const float aco   = sigmoidf_(al_raw[0]);
    const float bco   = sigmoidf_(be_raw[0]) * (1.0f - aco * 0.99f);
    const float gma   = gam[0];

    // address bases
    const int rdF = lane * 8;                                                  // + buf + kt*512
    const int wrB = (w >> 1) * 512 + (n + 16 * ((2 * w + (lg >> 1)) & 3)) * 8 + (lg & 1) * 4;
    const int pvB = 12288 + w * 64 + lg * 16;                                  // + p*1024
    const int xvB = 20480 + n * 1028;                                          // + tt*4

    f32x4 h_own = (f32x4){0.f, 0.f, 0.f, 0.f};
    f32x4 zst;
    float sg = 1e-6f, xp = 0.f;

    __syncthreads();

    int hb = 0;
    for (int tt = 0; tt < TT; ++tt) {
        const float xc = *(const float*)(lds + xvB + tt * 4);

        // ---- phase A: Cz = h@Uz, Cr = h@Ur ----
        f32x4 Cz = (f32x4){0.f, 0.f, 0.f, 0.f};
        f32x4 Cr = (f32x4){0.f, 0.f, 0.f, 0.f};
#pragma unroll
        for (int kt = 0; kt < 8; ++kt) {
            long hv = *(const long*)(lds + hb + rdF + kt * 512);
            Cz = __builtin_amdgcn_mfma_f32_16x16x32_fp8_fp8(Wz[kt], hv, Cz, 0, 0, 0);
            Cr = __builtin_amdgcn_mfma_f32_16x16x32_fp8_fp8(Wr[kt], hv, Cr, 0, 0, 0);
        }
        // elementwise z, r; write r*h (fp8, one b32)
        {
            f32x4 wzv = *(const f32x4*)(lds + pvB + 0 * 1024);
            f32x4 bzv = *(const f32x4*)(lds + pvB + 1 * 1024);
            f32x4 wrv = *(const f32x4*)(lds + pvB + 2 * 1024);
            f32x4 brv = *(const f32x4*)(lds + pvB + 3 * 1024);
            float rh[4];
#pragma unroll
            for (int i = 0; i < 4; ++i) {
                zst[i]   = sigmoidf_(Cz[i] + xc * wzv[i] + bzv[i]);
                float rv = sigmoidf_(Cr[i] + xc * wrv[i] + brv[i]);
                rh[i]    = rv * h_own[i];
            }
            *(unsigned*)(lds + 8192 + wrB) = pk4_fp8(rh[0], rh[1], rh[2], rh[3]);
        }
        __syncthreads();

        // ---- phase B: Ch = (r*h)@Uh ----
        f32x4 Ch = (f32x4){0.f, 0.f, 0.f, 0.f};
#pragma unroll
        for (int kt = 0; kt < 8; ++kt) {
            long rv8 = *(const long*)(lds + 8192 + rdF + kt * 512);
            Ch = __builtin_amdgcn_mfma_f32_16x16x32_fp8_fp8(Wh[kt], rv8, Ch, 0, 0, 0);
        }
        // garch recurrence (row-n scalar; uses x[tt-1])
        float ep = (tt == 0) ? 1e-6f : xp * xp;
        float gv = omega + aco * ep + bco * sg;
        sg = gv;
        // elementwise h_new; write h (fp8, other buffer)
        {
            f32x4 whv = *(const f32x4*)(lds + pvB + 4 * 1024);
            f32x4 bhv = *(const f32x4*)(lds + pvB + 5 * 1024);
            f32x4 wgv = *(const f32x4*)(lds + pvB + 6 * 1024);
            f32x4 bgv = *(const f32x4*)(lds + pvB + 7 * 1024);
            float hn[4];
#pragma unroll
            for (int i = 0; i < 4; ++i) {
                float htld = tanhf_(Ch[i] + xc * whv[i] + bhv[i]);
                float zv   = zst[i];
                float hh   = (1.f - zv) * htld + zv * h_own[i];
                hn[i]      = tanhf_(hh + gma * (gv * wgv[i] + bgv[i]));
                h_own[i]   = hn[i];
            }
            *(unsigned*)(lds + (hb ^ 4096) + wrB) = pk4_fp8(hn[0], hn[1], hn[2], hn[3]);
        }
        xp = xc;
        hb ^= 4096;
        __syncthreads();
    }

    // ---- stash exact fp32 h (overlay, 16 KB at 0) + sigma_sq ----
    {
        float* hsF = (float*)lds;
#pragma unroll
        for (int i = 0; i < 4; ++i)
            hsF[n * 256 + 16 * w + lg * 4 + i] = h_own[i];
        if (w == 0 && lg == 0) ((float*)(lds + 36928))[n] = sg;
    }
    __syncthreads();

    // ---- head: hid = relu(h @ fc1 + b1) ----
    {
        const int j = t & 255, q = t >> 8;      // q: rows q*4 .. +3
        const float* hsF = (const float*)lds;
        float acc[4];
#pragma unroll
        for (int r = 0; r < 4; ++r) acc[r] = 0.f;
#pragma unroll 4
        for (int k = 0; k < HH; ++k) {
            float wv = fc1w[k * HH + j];
#pragma unroll
            for (int r = 0; r < 4; ++r) acc[r] += hsF[(q * 4 + r) * 256 + k] * wv;
        }
        float* hid = (float*)(lds + 16384);
        const float b1 = fc1b[j];
#pragma unroll
        for (int r = 0; r < 4; ++r) hid[(q * 4 + r) * 256 + j] = fmaxf(acc[r] + b1, 0.f);
    }
    __syncthreads();

    // ---- head: nn_scale / vol ----
    if (t < ROWS * HOR) {
        const int b = t / HOR, c = t % HOR;
        const float* hid = (const float*)(lds + 16384);
        float acc = fc2b[c];
        for (int k = 0; k < HH; ++k) acc += hid[b * 256 + k] * fc2w[k * HOR + c];
        const float sp  = log1pf(__expf(acc));
        const float sgv = ((const float*)(lds + 36928))[b];
        const float vb  = sqrtf(sgv + 1e-8f);
        float vol = vb * (1.0f + sp);
        vol = fminf(fmaxf(vol, 0.01f), 10.0f);
        out[(b0 + b) * HOR + c] = vol;
    }
    if (t < ROWS) out[BATCH * HOR + b0 + t] = ((const float*)(lds + 36928))[t];
}

extern "C" void kernel_launch(void* const* d_in, const int* in_sizes, int n_in,
                              void* d_out, int out_size, void* d_ws, size_t ws_size,
                              hipStream_t stream) {
    const float* x    = (const float*)d_in[0];
    const float* Wzw  = (const float*)d_in[1];
    const float* Wzb  = (const float*)d_in[2];
    const float* Uzw  = (const float*)d_in[3];
    const float* Uzb  = (const float*)d_in[4];
    const float* Wrw  = (const float*)d_in[5];
    const float* Wrb  = (const float*)d_in[6];
    const float* Urw  = (const float*)d_in[7];
    const float* Urb  = (const float*)d_in[8];
    const float* Whw  = (const float*)d_in[9];
    const float* Whb  = (const float*)d_in[10];
    const float* Uhw  = (const float*)d_in[11];
    const float* Uhb  = (const float*)d_in[12];
    const float* Wgw  = (const float*)d_in[13];
    const float* Wgb  = (const float*)d_in[14];
    const float* om   = (const float*)d_in[15];
    const float* al   = (const float*)d_in[16];
    const float* be   = (const float*)d_in[17];
    const float* ga   = (const float*)d_in[18];
    const float* fc1w = (const float*)d_in[19];
    const float* fc1b = (const float*)d_in[20];
    const float* fc2w = (const float*)d_in[21];
    const float* fc2b = (const float*)d_in[22];

    uint2* UB = (uint2*)d_ws;   // 24576 x 8B fp8 fragments = 192 KB

    prep_kernel<<<96, 256, 0, stream>>>(Uzw, Urw, Uhw, UB);
    gru_kernel<<<32, 1024, 0, stream>>>(x, Wzw, Wzb, Uzb, Wrw, Wrb, Urb, Whw, Whb, Uhb,
                                        Wgw, Wgb, om, al, be, ga, fc1w, fc1b, fc2w, fc2b,
                                        (const long*)UB, (float*)d_out);
}

// Round 9
// 551.055 us; speedup vs baseline: 1.6965x; 1.0427x over previous
//
#include <hip/hip_runtime.h>

#define BATCH 512
#define TT 256
#define HH 256
#define HOR 22
#define ROWS 16

typedef __attribute__((ext_vector_type(4))) float f32x4;
// 16-byte aligned pair of 64-bit fragments (plain struct — avoids the
// ext_vector_type(2)-of-long construct from R7, suspected in the container
// failures; an aligned 16B aggregate load still compiles to ds_read_b128).
struct __align__(16) lpair { long x, y; };

__device__ __forceinline__ float rcp_(float x) { return __builtin_amdgcn_rcpf(x); }
__device__ __forceinline__ float sigmoidf_(float x) { return rcp_(1.0f + __expf(-x)); }
__device__ __forceinline__ float tanhf_(float x) {
    float e = __expf(-2.0f * fabsf(x));
    float t = (1.0f - e) * rcp_(1.0f + e);
    return copysignf(t, x);
}
// pack 4 floats -> 4 fp8 e4m3 bytes (little-endian order v0..v3)
__device__ __forceinline__ unsigned pk4_fp8(float v0, float v1, float v2, float v3) {
    int w = 0;
    w = __builtin_amdgcn_cvt_pk_fp8_f32(v0, v1, w, false);
    w = __builtin_amdgcn_cvt_pk_fp8_f32(v2, v3, w, true);
    return (unsigned)w;
}
#define PIN64(v) asm volatile("" : "+v"(v))

// ---------------- prep: U matrices -> fp8 MFMA A-fragment layout ----------------
// A-frag for (gate, col-tile ct, kt): lane holds 8 fp8 of A[m][k] = U[k][col],
// col = ct*16 + (lane&15), k = kt*32 + (lane>>4)*8 + j (j = byte 0..7).
__global__ __launch_bounds__(256) void prep_kernel(const float* __restrict__ Uz,
                                                   const float* __restrict__ Ur,
                                                   const float* __restrict__ Uh,
                                                   uint2* __restrict__ UB) {
    int tid  = blockIdx.x * 256 + threadIdx.x;   // 0 .. 24575
    int gate = tid >> 13;                         // 3 gates x 8192
    int rem  = tid & 8191;
    int ct   = rem >> 9;                          // 0..15
    int kt   = (rem >> 6) & 7;                    // 0..7
    int lane = rem & 63;
    int col  = ct * 16 + (lane & 15);
    int kb   = kt * 32 + (lane >> 4) * 8;
    const float* src = (gate == 0) ? Uz : (gate == 1) ? Ur : Uh;
    float f[8];
#pragma unroll
    for (int j = 0; j < 8; ++j) f[j] = src[(kb + j) * HH + col];
    uint2 v;
    v.x = pk4_fp8(f[0], f[1], f[2], f[3]);
    v.y = pk4_fp8(f[4], f[5], f[6], f[7]);
    UB[tid] = v;
}

// ---------------- persistent GRU: 1 WG = 16 rows, 16 waves, 4 waves/SIMD ----------------
// R6 post-mortem: occupancy doubling gained only 7% -> bottleneck = per-CU LDS
// port (~27 LDS ops/thread/step, incl. 8 loop-invariant param b128 re-reads).
// This round: params HOISTED to 32 VGPRs (loop-invariant), and h/rh fragments
// PAIRED so one ds_read_b128 feeds two MFMAs: 27 -> 11 LDS ops/thread/step.
// Same math, same accumulation order -> bit-identical to R6.
//
// Wave w owns m-tile w (U-cols [16w,16w+16)), 3 gates: 24 frags x 2 = 48 regs.
// Thread owns batch row n = lane&15, cols 16w + lg*4 + i.
// h/rh fp8 PAIRED B-frag layout: element (k,n) at byte
//   (k>>6)*1024 + (n + 16*((k>>3)&3))*16 + ((k>>5)&1)*8 + (k&7)
// Writer (w,lg,n): one b32 at
//   (w>>2)*1024 + (n + 16*((2w+(lg>>1))&3))*16 + ((w>>1)&1)*8 + (lg&1)*4
// Reader lane l, pair p: b128 at p*1024 + l*16 -> (kt=2p, kt=2p+1) fragments.
//
// LDS map (bytes):
//   0     : hB buf0  (4 KB)
//   4096  : hB buf1  (4 KB)
//   8192  : rhB      (4 KB)
//   12288 : params   (8 KB)  8 planes x 256 f32 (read ONCE pre-loop)
//   20480 : xs       (16.07 KB) 16 rows x 1028 B
//   36928 : sigL     (64 B)
//   epilogue overlays: hsF f32[16][256] at 0, hid f32[16][256] at 16384
__global__ __launch_bounds__(1024) __attribute__((amdgpu_waves_per_eu(4, 4))) void gru_kernel(
    const float* __restrict__ x,
    const float* __restrict__ Wzw, const float* __restrict__ Wzb, const float* __restrict__ Uzb,
    const float* __restrict__ Wrw, const float* __restrict__ Wrb, const float* __restrict__ Urb,
    const float* __restrict__ Whw, const float* __restrict__ Whb, const float* __restrict__ Uhb,
    const float* __restrict__ Wgw, const float* __restrict__ Wgb,
    const float* __restrict__ om_raw, const float* __restrict__ al_raw,
    const float* __restrict__ be_raw, const float* __restrict__ gam,
    const float* __restrict__ fc1w, const float* __restrict__ fc1b,
    const float* __restrict__ fc2w, const float* __restrict__ fc2b,
    const long* __restrict__ UBL,
    float* __restrict__ out) {

    __shared__ __align__(16) char lds[36992];

    const int t    = threadIdx.x;
    const int w    = t >> 6;        // wave 0..15, owns m-tile w
    const int lane = t & 63;
    const int n    = lane & 15;     // owned batch row
    const int lg   = lane >> 4;     // lane group 0..3
    const int b0   = blockIdx.x * ROWS;

    // ---- weights: 48 VGPRs of fp8 fragments ----
    long Wz[8], Wr[8], Wh[8];
#pragma unroll
    for (int kt = 0; kt < 8; ++kt) {
        Wz[kt] = UBL[((0 * 16 + w) * 8 + kt) * 64 + lane];
        Wr[kt] = UBL[((1 * 16 + w) * 8 + kt) * 64 + lane];
        Wh[kt] = UBL[((2 * 16 + w) * 8 + kt) * 64 + lane];
    }
#pragma unroll
    for (int kt = 0; kt < 8; ++kt) { PIN64(Wz[kt]); PIN64(Wr[kt]); PIN64(Wh[kt]); }

    // ---- stage x rows (padded 1028B stride) ----
#pragma unroll
    for (int it = 0; it < 4; ++it) {
        int i = t + it * 1024;                  // 0..4095
        int r = i >> 8, tp = i & 255;
        *(float*)(lds + 20480 + r * 1028 + tp * 4) = x[(b0 + r) * TT + tp];
    }
    // ---- per-column param table (consumed once, right below) ----
#pragma unroll
    for (int it = 0; it < 2; ++it) {
        int i = t + it * 1024;                  // 0..2047
        int p = i >> 8, c = i & 255;
        float v;
        switch (p) {
            case 0: v = Wzw[c]; break;
            case 1: v = Wzb[c] + Uzb[c]; break;
            case 2: v = Wrw[c]; break;
            case 3: v = Wrb[c] + Urb[c]; break;
            case 4: v = Whw[c]; break;
            case 5: v = Whb[c] + Uhb[c]; break;
            case 6: v = Wgw[c]; break;
            default: v = Wgb[c]; break;
        }
        *(float*)(lds + 12288 + p * 1024 + c * 4) = v;
    }
    // ---- zero h buffer 0 ----
    ((unsigned*)lds)[t] = 0;

    // scalar params (uniform -> SGPRs)
    const float omega = log1pf(__expf(om_raw[0])) + 1e-6f;
    const float aco   = sigmoidf_(al_raw[0]);
    const float bco   = sigmoidf_(be_raw[0]) * (1.0f - aco * 0.99f);
    const float gma   = gam[0];

    // address bases
    const int rdF = lane * 16;                                                 // + buf + p*1024
    const int wrB = (w >> 2) * 1024 + (n + 16 * ((2 * w + (lg >> 1)) & 3)) * 16
                  + ((w >> 1) & 1) * 8 + (lg & 1) * 4;
    const int pvB = 12288 + w * 64 + lg * 16;                                  // + p*1024
    const int xvB = 20480 + n * 1028;                                          // + tt*4

    __syncthreads();

    // ---- hoist params into registers (loop-invariant; kills 8 b128/step) ----
    const f32x4 wzv = *(const f32x4*)(lds + pvB + 0 * 1024);
    const f32x4 bzv = *(const f32x4*)(lds + pvB + 1 * 1024);
    const f32x4 wrv = *(const f32x4*)(lds + pvB + 2 * 1024);
    const f32x4 brv = *(const f32x4*)(lds + pvB + 3 * 1024);
    const f32x4 whv = *(const f32x4*)(lds + pvB + 4 * 1024);
    const f32x4 bhv = *(const f32x4*)(lds + pvB + 5 * 1024);
    const f32x4 wgv = *(const f32x4*)(lds + pvB + 6 * 1024);
    const f32x4 bgv = *(const f32x4*)(lds + pvB + 7 * 1024);

    f32x4 h_own = (f32x4){0.f, 0.f, 0.f, 0.f};
    f32x4 zst;
    float sg = 1e-6f, xp = 0.f;

    int hb = 0;
    for (int tt = 0; tt < TT; ++tt) {
        const float xc = *(const float*)(lds + xvB + tt * 4);

        // ---- phase A: Cz = h@Uz, Cr = h@Ur (4 x b128, paired fragments) ----
        f32x4 Cz = (f32x4){0.f, 0.f, 0.f, 0.f};
        f32x4 Cr = (f32x4){0.f, 0.f, 0.f, 0.f};
#pragma unroll
        for (int p = 0; p < 4; ++p) {
            lpair hv = *(const lpair*)(lds + hb + rdF + p * 1024);
            Cz = __builtin_amdgcn_mfma_f32_16x16x32_fp8_fp8(Wz[2 * p],     hv.x, Cz, 0, 0, 0);
            Cz = __builtin_amdgcn_mfma_f32_16x16x32_fp8_fp8(Wz[2 * p + 1], hv.y, Cz, 0, 0, 0);
            Cr = __builtin_amdgcn_mfma_f32_16x16x32_fp8_fp8(Wr[2 * p],     hv.x, Cr, 0, 0, 0);
            Cr = __builtin_amdgcn_mfma_f32_16x16x32_fp8_fp8(Wr[2 * p + 1], hv.y, Cr, 0, 0, 0);
        }
        // elementwise z, r; write r*h (fp8, one b32)
        {
            float rh[4];
#pragma unroll
            for (int i = 0; i < 4; ++i) {
                zst[i]   = sigmoidf_(Cz[i] + xc * wzv[i] + bzv[i]);
                float rv = sigmoidf_(Cr[i] + xc * wrv[i] + brv[i]);
                rh[i]    = rv * h_own[i];
            }
            *(unsigned*)(lds + 8192 + wrB) = pk4_fp8(rh[0], rh[1], rh[2], rh[3]);
        }
        __syncthreads();

        // ---- phase B: Ch = (r*h)@Uh ----
        f32x4 Ch = (f32x4){0.f, 0.f, 0.f, 0.f};
#pragma unroll
        for (int p = 0; p < 4; ++p) {
            lpair rv8 = *(const lpair*)(lds + 8192 + rdF + p * 1024);
            Ch = __builtin_amdgcn_mfma_f32_16x16x32_fp8_fp8(Wh[2 * p],     rv8.x, Ch, 0, 0, 0);
            Ch = __builtin_amdgcn_mfma_f32_16x16x32_fp8_fp8(Wh[2 * p + 1], rv8.y, Ch, 0, 0, 0);
        }
        // garch recurrence (row-n scalar; uses x[tt-1])
        float ep = (tt == 0) ? 1e-6f : xp * xp;
        float gv = omega + aco * ep + bco * sg;
        sg = gv;
        // elementwise h_new; write h (fp8, other buffer)
        {
            float hn[4];
#pragma unroll
            for (int i = 0; i < 4; ++i) {
                float htld = tanhf_(Ch[i] + xc * whv[i] + bhv[i]);
                float zv   = zst[i];
                float hh   = (1.f - zv) * htld + zv * h_own[i];
                hn[i]      = tanhf_(hh + gma * (gv * wgv[i] + bgv[i]));
                h_own[i]   = hn[i];
            }
            *(unsigned*)(lds + (hb ^ 4096) + wrB) = pk4_fp8(hn[0], hn[1], hn[2], hn[3]);
        }
        xp = xc;
        hb ^= 4096;
        __syncthreads();
    }

    // ---- stash exact fp32 h (overlay, 16 KB at 0) + sigma_sq ----
    {
        float* hsF = (float*)lds;
#pragma unroll
        for (int i = 0; i < 4; ++i)
            hsF[n * 256 + 16 * w + lg * 4 + i] = h_own[i];
        if (w == 0 && lg == 0) ((float*)(lds + 36928))[n] = sg;
    }
    __syncthreads();

    // ---- head: hid = relu(h @ fc1 + b1) ----
    {
        const int j = t & 255, q = t >> 8;      // q: rows q*4 .. +3
        const float* hsF = (const float*)lds;
        float acc[4];
#pragma unroll
        for (int r = 0; r < 4; ++r) acc[r] = 0.f;
#pragma unroll 4
        for (int k = 0; k < HH; ++k) {
            float wv = fc1w[k * HH + j];
#pragma unroll
            for (int r = 0; r < 4; ++r) acc[r] += hsF[(q * 4 + r) * 256 + k] * wv;
        }
        float* hid = (float*)(lds + 16384);
        const float b1 = fc1b[j];
#pragma unroll
        for (int r = 0; r < 4; ++r) hid[(q * 4 + r) * 256 + j] = fmaxf(acc[r] + b1, 0.f);
    }
    __syncthreads();

    // ---- head: nn_scale / vol ----
    if (t < ROWS * HOR) {
        const int b = t / HOR, c = t % HOR;
        const float* hid = (const float*)(lds + 16384);
        float acc = fc2b[c];
        for (int k = 0; k < HH; ++k) acc += hid[b * 256 + k] * fc2w[k * HOR + c];
        const float sp  = log1pf(__expf(acc));
        const float sgv = ((const float*)(lds + 36928))[b];
        const float vb  = sqrtf(sgv + 1e-8f);
        float vol = vb * (1.0f + sp);
        vol = fminf(fmaxf(vol, 0.01f), 10.0f);
        out[(b0 + b) * HOR + c] = vol;
    }
    if (t < ROWS) out[BATCH * HOR + b0 + t] = ((const float*)(lds + 36928))[t];
}

extern "C" void kernel_launch(void* const* d_in, const int* in_sizes, int n_in,
                              void* d_out, int out_size, void* d_ws, size_t ws_size,
                              hipStream_t stream) {
    const float* x    = (const float*)d_in[0];
    const float* Wzw  = (const float*)d_in[1];
    const float* Wzb  = (const float*)d_in[2];
    const float* Uzw  = (const float*)d_in[3];
    const float* Uzb  = (const float*)d_in[4];
    const float* Wrw  = (const float*)d_in[5];
    const float* Wrb  = (const float*)d_in[6];
    const float* Urw  = (const float*)d_in[7];
    const float* Urb  = (const float*)d_in[8];
    const float* Whw  = (const float*)d_in[9];
    const float* Whb  = (const float*)d_in[10];
    const float* Uhw  = (const float*)d_in[11];
    const float* Uhb  = (const float*)d_in[12];
    const float* Wgw  = (const float*)d_in[13];
    const float* Wgb  = (const float*)d_in[14];
    const float* om   = (const float*)d_in[15];
    const float* al   = (const float*)d_in[16];
    const float* be   = (const float*)d_in[17];
    const float* ga   = (const float*)d_in[18];
    const float* fc1w = (const float*)d_in[19];
    const float* fc1b = (const float*)d_in[20];
    const float* fc2w = (const float*)d_in[21];
    const float* fc2b = (const float*)d_in[22];

    uint2* UB = (uint2*)d_ws;   // 24576 x 8B fp8 fragments = 192 KB

    prep_kernel<<<96, 256, 0, stream>>>(Uzw, Urw, Uhw, UB);
    gru_kernel<<<32, 1024, 0, stream>>>(x, Wzw, Wzb, Uzb, Wrw, Wrb, Urb, Whw, Whb, Uhb,
                                        Wgw, Wgb, om, al, be, ga, fc1w, fc1b, fc2w, fc2b,
                                        (const long*)UB, (float*)d_out);
}

// Round 10
// 542.125 us; speedup vs baseline: 1.7244x; 1.0165x over previous
//
#include <hip/hip_runtime.h>

#define BATCH 512
#define TT 256
#define HH 256
#define HOR 22
#define ROWS 16

typedef __attribute__((ext_vector_type(4))) float f32x4;
// 16-byte aligned pair of 64-bit fragments (aligned 16B aggregate load -> ds_read_b128)
struct __align__(16) lpair { long x, y; };

__device__ __forceinline__ float rcp_(float x) { return __builtin_amdgcn_rcpf(x); }
__device__ __forceinline__ float sigmoidf_(float x) { return rcp_(1.0f + __expf(-x)); }
// tanh(x) = 1 - 2/(e^{2x}+1): 5-6 inst (add, exp, add, rcp, fma), branch-free,
// saturates correctly (e^{2x}->inf => rcp->0 => +1; ->0 => -1). Replaces the
// ~10-inst abs/copysign form; R9 counters show VALU inst count is the
// critical path (75% VALUBusy per active CU).
__device__ __forceinline__ float tanhf_(float x) {
    float e2 = __expf(x + x);
    return 1.0f - 2.0f * rcp_(1.0f + e2);
}
// pack 4 floats -> 4 fp8 e4m3 bytes (little-endian order v0..v3)
__device__ __forceinline__ unsigned pk4_fp8(float v0, float v1, float v2, float v3) {
    int w = 0;
    w = __builtin_amdgcn_cvt_pk_fp8_f32(v0, v1, w, false);
    w = __builtin_amdgcn_cvt_pk_fp8_f32(v2, v3, w, true);
    return (unsigned)w;
}
#define PIN64(v) asm volatile("" : "+v"(v))

// ---------------- prep: U matrices -> fp8 MFMA A-fragment layout ----------------
// A-frag for (gate, col-tile ct, kt): lane holds 8 fp8 of A[m][k] = U[k][col],
// col = ct*16 + (lane&15), k = kt*32 + (lane>>4)*8 + j (j = byte 0..7).
__global__ __launch_bounds__(256) void prep_kernel(const float* __restrict__ Uz,
                                                   const float* __restrict__ Ur,
                                                   const float* __restrict__ Uh,
                                                   uint2* __restrict__ UB) {
    int tid  = blockIdx.x * 256 + threadIdx.x;   // 0 .. 24575
    int gate = tid >> 13;                         // 3 gates x 8192
    int rem  = tid & 8191;
    int ct   = rem >> 9;                          // 0..15
    int kt   = (rem >> 6) & 7;                    // 0..7
    int lane = rem & 63;
    int col  = ct * 16 + (lane & 15);
    int kb   = kt * 32 + (lane >> 4) * 8;
    const float* src = (gate == 0) ? Uz : (gate == 1) ? Ur : Uh;
    float f[8];
#pragma unroll
    for (int j = 0; j < 8; ++j) f[j] = src[(kb + j) * HH + col];
    uint2 v;
    v.x = pk4_fp8(f[0], f[1], f[2], f[3]);
    v.y = pk4_fp8(f[4], f[5], f[6], f[7]);
    UB[tid] = v;
}

// ---------------- persistent GRU: 1 WG = 16 rows, 16 waves, 4 waves/SIMD ----------------
// R9 post-mortem: VALU pipe is the critical path (75% busy per active CU;
// LDS-halving gained only 7%). This round: transcendental instruction diet
// (5-inst tanh, h_hat = htld + z*(h-htld)) — ~25% fewer VALU inst/step.
// Structure, layout, MFMA order identical to R9.
//
// Wave w owns m-tile w (U-cols [16w,16w+16)), 3 gates: 24 frags x 2 = 48 regs
// (AGPR-resident, read natively by MFMA; R9 measured VGPR=64, no spills).
// Thread owns batch row n = lane&15, cols 16w + lg*4 + i.
// h/rh fp8 PAIRED B-frag layout: element (k,n) at byte
//   (k>>6)*1024 + (n + 16*((k>>3)&3))*16 + ((k>>5)&1)*8 + (k&7)
// Writer (w,lg,n): one b32 at
//   (w>>2)*1024 + (n + 16*((2w+(lg>>1))&3))*16 + ((w>>1)&1)*8 + (lg&1)*4
// Reader lane l, pair p: b128 at p*1024 + l*16 -> (kt=2p, kt=2p+1) fragments.
//
// LDS map (bytes):
//   0     : hB buf0  (4 KB)
//   4096  : hB buf1  (4 KB)
//   8192  : rhB      (4 KB)
//   12288 : params   (8 KB)  8 planes x 256 f32 (read ONCE pre-loop)
//   20480 : xs       (16.07 KB) 16 rows x 1028 B
//   36928 : sigL     (64 B)
//   epilogue overlays: hsF f32[16][256] at 0, hid f32[16][256] at 16384
__global__ __launch_bounds__(1024) __attribute__((amdgpu_waves_per_eu(4, 4))) void gru_kernel(
    const float* __restrict__ x,
    const float* __restrict__ Wzw, const float* __restrict__ Wzb, const float* __restrict__ Uzb,
    const float* __restrict__ Wrw, const float* __restrict__ Wrb, const float* __restrict__ Urb,
    const float* __restrict__ Whw, const float* __restrict__ Whb, const float* __restrict__ Uhb,
    const float* __restrict__ Wgw, const float* __restrict__ Wgb,
    const float* __restrict__ om_raw, const float* __restrict__ al_raw,
    const float* __restrict__ be_raw, const float* __restrict__ gam,
    const float* __restrict__ fc1w, const float* __restrict__ fc1b,
    const float* __restrict__ fc2w, const float* __restrict__ fc2b,
    const long* __restrict__ UBL,
    float* __restrict__ out) {

    __shared__ __align__(16) char lds[36992];

    const int t    = threadIdx.x;
    const int w    = t >> 6;        // wave 0..15, owns m-tile w
    const int lane = t & 63;
    const int n    = lane & 15;     // owned batch row
    const int lg   = lane >> 4;     // lane group 0..3
    const int b0   = blockIdx.x * ROWS;

    // ---- weights: 48 regs of fp8 fragments (land in AGPRs) ----
    long Wz[8], Wr[8], Wh[8];
#pragma unroll
    for (int kt = 0; kt < 8; ++kt) {
        Wz[kt] = UBL[((0 * 16 + w) * 8 + kt) * 64 + lane];
        Wr[kt] = UBL[((1 * 16 + w) * 8 + kt) * 64 + lane];
        Wh[kt] = UBL[((2 * 16 + w) * 8 + kt) * 64 + lane];
    }
#pragma unroll
    for (int kt = 0; kt < 8; ++kt) { PIN64(Wz[kt]); PIN64(Wr[kt]); PIN64(Wh[kt]); }

    // ---- stage x rows (padded 1028B stride) ----
#pragma unroll
    for (int it = 0; it < 4; ++it) {
        int i = t + it * 1024;                  // 0..4095
        int r = i >> 8, tp = i & 255;
        *(float*)(lds + 20480 + r * 1028 + tp * 4) = x[(b0 + r) * TT + tp];
    }
    // ---- per-column param table (consumed once, right below) ----
#pragma unroll
    for (int it = 0; it < 2; ++it) {
        int i = t + it * 1024;                  // 0..2047
        int p = i >> 8, c = i & 255;
        float v;
        switch (p) {
            case 0: v = Wzw[c]; break;
            case 1: v = Wzb[c] + Uzb[c]; break;
            case 2: v = Wrw[c]; break;
            case 3: v = Wrb[c] + Urb[c]; break;
            case 4: v = Whw[c]; break;
            case 5: v = Whb[c] + Uhb[c]; break;
            case 6: v = Wgw[c]; break;
            default: v = Wgb[c]; break;
        }
        *(float*)(lds + 12288 + p * 1024 + c * 4) = v;
    }
    // ---- zero h buffer 0 ----
    ((unsigned*)lds)[t] = 0;

    // scalar params (uniform -> SGPRs)
    const float omega = log1pf(__expf(om_raw[0])) + 1e-6f;
    const float aco   = sigmoidf_(al_raw[0]);
    const float bco   = sigmoidf_(be_raw[0]) * (1.0f - aco * 0.99f);
    const float gma   = gam[0];

    // address bases
    const int rdF = lane * 16;                                                 // + buf + p*1024
    const int wrB = (w >> 2) * 1024 + (n + 16 * ((2 * w + (lg >> 1)) & 3)) * 16
                  + ((w >> 1) & 1) * 8 + (lg & 1) * 4;
    const int pvB = 12288 + w * 64 + lg * 16;                                  // + p*1024
    const int xvB = 20480 + n * 1028;                                          // + tt*4

    __syncthreads();

    // ---- hoist params into registers (loop-invariant) ----
    const f32x4 wzv = *(const f32x4*)(lds + pvB + 0 * 1024);
    const f32x4 bzv = *(const f32x4*)(lds + pvB + 1 * 1024);
    const f32x4 wrv = *(const f32x4*)(lds + pvB + 2 * 1024);
    const f32x4 brv = *(const f32x4*)(lds + pvB + 3 * 1024);
    const f32x4 whv = *(const f32x4*)(lds + pvB + 4 * 1024);
    const f32x4 bhv = *(const f32x4*)(lds + pvB + 5 * 1024);
    const f32x4 wgv = *(const f32x4*)(lds + pvB + 6 * 1024);
    const f32x4 bgv = *(const f32x4*)(lds + pvB + 7 * 1024);

    f32x4 h_own = (f32x4){0.f, 0.f, 0.f, 0.f};
    f32x4 zst;
    float sg = 1e-6f, xp = 0.f;

    int hb = 0;
    for (int tt = 0; tt < TT; ++tt) {
        const float xc = *(const float*)(lds + xvB + tt * 4);

        // ---- phase A: Cz = h@Uz, Cr = h@Ur (4 x b128, paired fragments) ----
        f32x4 Cz = (f32x4){0.f, 0.f, 0.f, 0.f};
        f32x4 Cr = (f32x4){0.f, 0.f, 0.f, 0.f};
#pragma unroll
        for (int p = 0; p < 4; ++p) {
            lpair hv = *(const lpair*)(lds + hb + rdF + p * 1024);
            Cz = __builtin_amdgcn_mfma_f32_16x16x32_fp8_fp8(Wz[2 * p],     hv.x, Cz, 0, 0, 0);
            Cz = __builtin_amdgcn_mfma_f32_16x16x32_fp8_fp8(Wz[2 * p + 1], hv.y, Cz, 0, 0, 0);
            Cr = __builtin_amdgcn_mfma_f32_16x16x32_fp8_fp8(Wr[2 * p],     hv.x, Cr, 0, 0, 0);
            Cr = __builtin_amdgcn_mfma_f32_16x16x32_fp8_fp8(Wr[2 * p + 1], hv.y, Cr, 0, 0, 0);
        }
        // elementwise z, r; write r*h (fp8, one b32)
        {
            float rh[4];
#pragma unroll
            for (int i = 0; i < 4; ++i) {
                zst[i]   = sigmoidf_(Cz[i] + xc * wzv[i] + bzv[i]);
                float rv = sigmoidf_(Cr[i] + xc * wrv[i] + brv[i]);
                rh[i]    = rv * h_own[i];
            }
            *(unsigned*)(lds + 8192 + wrB) = pk4_fp8(rh[0], rh[1], rh[2], rh[3]);
        }
        __syncthreads();

        // ---- phase B: Ch = (r*h)@Uh ----
        f32x4 Ch = (f32x4){0.f, 0.f, 0.f, 0.f};
#pragma unroll
        for (int p = 0; p < 4; ++p) {
            lpair rv8 = *(const lpair*)(lds + 8192 + rdF + p * 1024);
            Ch = __builtin_amdgcn_mfma_f32_16x16x32_fp8_fp8(Wh[2 * p],     rv8.x, Ch, 0, 0, 0);
            Ch = __builtin_amdgcn_mfma_f32_16x16x32_fp8_fp8(Wh[2 * p + 1], rv8.y, Ch, 0, 0, 0);
        }
        // garch recurrence (row-n scalar; uses x[tt-1])
        float ep = (tt == 0) ? 1e-6f : xp * xp;
        float gv = omega + aco * ep + bco * sg;
        sg = gv;
        // elementwise h_new; write h (fp8, other buffer)
        {
            float hn[4];
#pragma unroll
            for (int i = 0; i < 4; ++i) {
                float htld = tanhf_(Ch[i] + xc * whv[i] + bhv[i]);
                // h_hat = (1-z)*htld + z*h  ==  htld + z*(h - htld)
                float hh   = htld + zst[i] * (h_own[i] - htld);
                hn[i]      = tanhf_(hh + gma * (gv * wgv[i] + bgv[i]));
                h_own[i]   = hn[i];
            }
            *(unsigned*)(lds + (hb ^ 4096) + wrB) = pk4_fp8(hn[0], hn[1], hn[2], hn[3]);
        }
        xp = xc;
        hb ^= 4096;
        __syncthreads();
    }

    // ---- stash exact fp32 h (overlay, 16 KB at 0) + sigma_sq ----
    {
        float* hsF = (float*)lds;
#pragma unroll
        for (int i = 0; i < 4; ++i)
            hsF[n * 256 + 16 * w + lg * 4 + i] = h_own[i];
        if (w == 0 && lg == 0) ((float*)(lds + 36928))[n] = sg;
    }
    __syncthreads();

    // ---- head: hid = relu(h @ fc1 + b1) ----
    {
        const int j = t & 255, q = t >> 8;      // q: rows q*4 .. +3
        const float* hsF = (const float*)lds;
        float acc[4];
#pragma unroll
        for (int r = 0; r < 4; ++r) acc[r] = 0.f;
#pragma unroll 4
        for (int k = 0; k < HH; ++k) {
            float wv = fc1w[k * HH + j];
#pragma unroll
            for (int r = 0; r < 4; ++r) acc[r] += hsF[(q * 4 + r) * 256 + k] * wv;
        }
        float* hid = (float*)(lds + 16384);
        const float b1 = fc1b[j];
#pragma unroll
        for (int r = 0; r < 4; ++r) hid[(q * 4 + r) * 256 + j] = fmaxf(acc[r] + b1, 0.f);
    }
    __syncthreads();

    // ---- head: nn_scale / vol ----
    if (t < ROWS * HOR) {
        const int b = t / HOR, c = t % HOR;
        const float* hid = (const float*)(lds + 16384);
        float acc = fc2b[c];
        for (int k = 0; k < HH; ++k) acc += hid[b * 256 + k] * fc2w[k * HOR + c];
        const float sp  = log1pf(__expf(acc));
        const float sgv = ((const float*)(lds + 36928))[b];
        const float vb  = sqrtf(sgv + 1e-8f);
        float vol = vb * (1.0f + sp);
        vol = fminf(fmaxf(vol, 0.01f), 10.0f);
        out[(b0 + b) * HOR + c] = vol;
    }
    if (t < ROWS) out[BATCH * HOR + b0 + t] = ((const float*)(lds + 36928))[t];
}

extern "C" void kernel_launch(void* const* d_in, const int* in_sizes, int n_in,
                              void* d_out, int out_size, void* d_ws, size_t ws_size,
                              hipStream_t stream) {
    const float* x    = (const float*)d_in[0];
    const float* Wzw  = (const float*)d_in[1];
    const float* Wzb  = (const float*)d_in[2];
    const float* Uzw  = (const float*)d_in[3];
    const float* Uzb  = (const float*)d_in[4];
    const float* Wrw  = (const float*)d_in[5];
    const float* Wrb  = (const float*)d_in[6];
    const float* Urw  = (const float*)d_in[7];
    const float* Urb  = (const float*)d_in[8];
    const float* Whw  = (const float*)d_in[9];
    const float* Whb  = (const float*)d_in[10];
    const float* Uhw  = (const float*)d_in[11];
    const float* Uhb  = (const float*)d_in[12];
    const float* Wgw  = (const float*)d_in[13];
    const float* Wgb  = (const float*)d_in[14];
    const float* om   = (const float*)d_in[15];
    const float* al   = (const float*)d_in[16];
    const float* be   = (const float*)d_in[17];
    const float* ga   = (const float*)d_in[18];
    const float* fc1w = (const float*)d_in[19];
    const float* fc1b = (const float*)d_in[20];
    const float* fc2w = (const float*)d_in[21];
    const float* fc2b = (const float*)d_in[22];

    uint2* UB = (uint2*)d_ws;   // 24576 x 8B fp8 fragments = 192 KB

    prep_kernel<<<96, 256, 0, stream>>>(Uzw, Urw, Uhw, UB);
    gru_kernel<<<32, 1024, 0, stream>>>(x, Wzw, Wzb, Uzb, Wrw, Wrb, Urb, Whw, Whb, Uhb,
                                        Wgw, Wgb, om, al, be, ga, fc1w, fc1b, fc2w, fc2b,
                                        (const long*)UB, (float*)d_out);
}